// Round 10
// baseline (264.660 us; speedup 1.0000x reference)
//
#include <hip/hip_runtime.h>

// IF (integrate-and-fire) forward, T=4 — R8: DISCRIMINATION ROUND (retry #2;
// prior submits hit GPUAcquisitionTimeout / container failure, never ran).
// Kernel 1 (copy_control): pure 1+1-stream float4 copy of the whole tensor —
//   calibrates the in-context read+write HBM ceiling (m13 replica).
// Kernel 2 (if_fwd_lds): real IF computation, but each WAVE has exactly one
//   contiguous read stream and one contiguous write stream (wave w <-> timestep
//   w), with the cross-timestep scan done via a conflict-free LDS transpose.
// rocprof reports each dispatch separately; total dur_us is sacrificed this
// round for the decisive per-kernel measurement.

typedef float f32x4 __attribute__((ext_vector_type(4)));

__global__ __launch_bounds__(256) void copy_control(
    const f32x4* __restrict__ x, f32x4* __restrict__ out)
{
    const int i = blockIdx.x * 1024 + threadIdx.x;
#pragma unroll
    for (int k = 0; k < 4; ++k)
        out[i + 256 * k] = x[i + 256 * k];
}

__device__ __forceinline__ f32x4 spike_of(f32x4& m, const f32x4 v, const float th) {
    m += v;
    f32x4 s;
    s.x = (m.x >= th) ? th : 0.0f;
    s.y = (m.y >= th) ? th : 0.0f;
    s.z = (m.z >= th) ? th : 0.0f;
    s.w = (m.w >= th) ? th : 0.0f;
    m -= s;
    return s;
}

__global__ __launch_bounds__(256) void if_fwd_lds(
    const f32x4* __restrict__ x,
    const float* __restrict__ thresh_p,
    f32x4* __restrict__ out,
    int n4,     // f32x4 positions per timestep (2,097,152)
    int chunk)  // f32x4 positions per block per timestep (4096)
{
    __shared__ f32x4 lds[4][1024];   // 64 KB

    const float th = thresh_p[0];
    const float m0 = 0.5f * th;

    const int tid  = threadIdx.x;
    const int wave = tid >> 6;       // 0..3 — this wave's timestep
    const int lane = tid & 63;
    const int blockBase = blockIdx.x * chunk;

    for (int it = 0; it < chunk; it += 1024) {
        const int base = blockBase + it;

        // Phase 1: wave w stages 16 KB of timestep w — ONE contiguous read
        // stream per wave (copy-identical address pattern).
        const f32x4* src = x + wave * n4 + base;
#pragma unroll
        for (int k = 0; k < 16; ++k)
            lds[wave][lane + 64 * k] = src[lane + 64 * k];
        __syncthreads();

        // Phase 2: per-position scan across t via LDS (16B-contiguous reads
        // and writes across lanes -> conflict-free). In-place update is safe:
        // only this thread touches lds[*][p].
#pragma unroll
        for (int j = 0; j < 4; ++j) {
            const int p = tid + 256 * j;
            f32x4 v0 = lds[0][p];
            f32x4 v1 = lds[1][p];
            f32x4 v2 = lds[2][p];
            f32x4 v3 = lds[3][p];
            f32x4 m = m0;
            lds[0][p] = spike_of(m, v0, th);
            lds[1][p] = spike_of(m, v1, th);
            lds[2][p] = spike_of(m, v2, th);
            lds[3][p] = spike_of(m, v3, th);
        }
        __syncthreads();

        // Phase 3: wave w stores 16 KB of timestep w — ONE contiguous write
        // stream per wave.
        f32x4* dst = out + wave * n4 + base;
#pragma unroll
        for (int k = 0; k < 16; ++k)
            dst[lane + 64 * k] = lds[wave][lane + 64 * k];
        __syncthreads();   // protect LDS reuse
    }
}

extern "C" void kernel_launch(void* const* d_in, const int* in_sizes, int n_in,
                              void* d_out, int out_size, void* d_ws, size_t ws_size,
                              hipStream_t stream) {
    const float* x      = (const float*)d_in[0];
    const float* thresh = (const float*)d_in[1];
    float* out          = (float*)d_out;

    const int total   = in_sizes[0];   // 33,554,432 (T=4)
    const int n_per_t = total / 4;     // 8,388,608
    const int n4      = n_per_t / 4;   // 2,097,152 f32x4 per timestep

    // Control first (wrong values), real kernel second (overwrites all of out).
    {
        const int flat4 = total / 4;           // 8,388,608 f32x4 total
        const int grid  = flat4 / 1024;        // 8192 blocks
        copy_control<<<grid, 256, 0, stream>>>((const f32x4*)x, (f32x4*)out);
    }
    {
        const int grid  = 512;
        const int chunk = n4 / grid;           // 4096
        if_fwd_lds<<<grid, 256, 0, stream>>>(
            (const f32x4*)x, thresh, (f32x4*)out, n4, chunk);
    }
}